// Round 22
// baseline (399.700 us; speedup 1.0000x reference)
//
#include <hip/hip_runtime.h>
#include <hip/hip_bf16.h>

#define TOK 9216   // 96*96 tokens per image
#define KSPLIT 5

typedef _Float16 half8 __attribute__((ext_vector_type(8)));
typedef float f32x4 __attribute__((ext_vector_type(4)));

// global_load_lds: 16B per lane, linear LDS dest (wave-uniform base + lane*16)
#define GLOAD_LDS(g, l) \
    __builtin_amdgcn_global_load_lds((const __attribute__((address_space(1))) void*)(g), \
                                     (__attribute__((address_space(3))) void*)(l), 16, 0, 0)

#define QSCALE 0.18033688011112042f   // 0.125 * log2(e); softmax runs in exp2 domain

// ---------------- workspace layout (in floats) ----------------
// [0, 2359296)        F1: conv1 out f16 [img][t][64]   (dead after conv2qkv ph1)
// [2359296, 4718592)  FEAT region (feat LDS-internal; dead)
// [4718592, 6488064)  QT | KT | VH  (f16; written conv2qkv ph2, read attn)
// [0, 4718592)        slabs 0-7 (attn partials; F1+FEAT dead by then)
// [6488064, 7667712)  slabs 8-9
// [7667712, 7852032)  ML2
// [7852032, 7852320)  CNT (288 ints; zeroed by conv2qkv each replay)
// [8257536, ...)      weights (W2T/B2/WCAT/BCAT)
#define OFF_F1   0u
#define SZ_F1    (4u*64u*TOK)            // 2359296
#define OFF_FEAT (OFF_F1 + SZ_F1)
#define SZ_FEAT  (2u*128u*TOK)           // 2359296
#define OFF_W1   (OFF_FEAT + SZ_FEAT + 3u*2u*64u*TOK)   // 8257536
#define OFF_B1   (OFF_W1 + 576u)
#define OFF_W2T  (OFF_B1 + 64u)          // WCONV f16 [64 co][576 k], k=tap*64+ci
#define OFF_B2   (OFF_W2T + 36864u)
#define OFF_WCAT (OFF_B2 + 64u)          // [192][128] f16, col k = n*64+c (q rows scaled)
#define OFF_BCAT (OFF_WCAT + 24576u)     // [192] f32 (qb scaled)

// QKV region disjoint from F1 (r21 race fix).
#define OFF_QT   4718592u                // [b][t][64] f16, scale folded
#define OFF_KT   5308416u                // [b][t][64] f16
#define OFF_VH   5898240u                // [b][64][t] f16, ends at 6488064

#define OFF_ML2  (OFF_FEAT + 9u*589824u) // 7667712: [slab][2 (m,l)][TOK] f32
#define OFF_CNT  7852032u                // 288 ints (one per (b,qt) group)

__device__ __forceinline__ const float* part_base_c(const float* ws, int slab) {
    return ws + (slab < 8 ? (unsigned)slab * 589824u
                          : 6488064u + (unsigned)(slab - 8) * 589824u);
}
__device__ __forceinline__ float* part_base(float* ws, int slab) {
    return ws + (slab < 8 ? (unsigned)slab * 589824u
                          : 6488064u + (unsigned)(slab - 8) * 589824u);
}

// ---------------- conv1 (+ merged weight prep): 1->64 ch, 3x3, relu; f16 channel-last ----
// grid 288x256: 2 threads per pixel (32 channels each).
__global__ __launch_bounds__(256) void conv1_kernel(
    const float* __restrict__ x,
    const float* __restrict__ w1, const float* __restrict__ b1,
    const float* __restrict__ w2, const float* __restrict__ b2,
    const float* __restrict__ qw, const float* __restrict__ qb,
    const float* __restrict__ kw, const float* __restrict__ kb,
    const float* __restrict__ vw, const float* __restrict__ vb,
    float* __restrict__ ws)
{
    int gid = blockIdx.x * 256 + threadIdx.x;   // 288*256 = 73728

    // ---- merged prep (each element written by exactly one thread) ----
    if (gid < 64) ws[OFF_B2 + gid] = b2[gid];
    if (gid < 36864) {   // WCONV f16: [co][tap*64+ci] <- w2[co][ci][tap]
        int co = gid / 576; int rem = gid % 576;
        int ci = rem / 9;  int tp = rem % 9;
        ((_Float16*)(ws + OFF_W2T))[co*576 + tp*64 + ci] = (_Float16)w2[gid];
    }
    if (gid < 24576) {   // WCAT f16, col k = n*64+c <- source col c*2+n; q rows scaled
        int o = gid >> 7; int kidx = gid & 127;
        int n = kidx >> 6, c = kidx & 63;
        int sc = c*2 + n;
        float v;
        if (o < 64)       v = qw[o*128 + sc] * QSCALE;
        else if (o < 128) v = kw[(o-64)*128 + sc];
        else              v = vw[(o-128)*128 + sc];
        ((_Float16*)(ws + OFF_WCAT))[gid] = (_Float16)v;
    }
    if (gid < 192) {
        float v;
        if (gid < 64)       v = qb[gid] * QSCALE;
        else if (gid < 128) v = kb[gid-64];
        else                v = vb[gid-128];
        ws[OFF_BCAT + gid] = v;
    }

    // ---- conv1: 2 threads/pixel ----
    _Float16* f1h = (_Float16*)(ws + OFF_F1);
    int px = gid >> 1, half = gid & 1;
    int img = px / TOK;
    int p   = px % TOK;
    int h = p / 96, w = p % 96;
    float xv[9];
    #pragma unroll
    for (int dh = 0; dh < 3; ++dh)
        #pragma unroll
        for (int dw = 0; dw < 3; ++dw) {
            int r = h + dh - 1, c = w + dw - 1;
            bool ok = (r >= 0) && (r < 96) && (c >= 0) && (c < 96);
            xv[dh*3 + dw] = ok ? x[img*TOK + r*96 + c] : 0.f;
        }
    _Float16* dst = f1h + (size_t)px * 64 + half * 32;
    #pragma unroll
    for (int g8 = 0; g8 < 4; ++g8) {
        union { _Float16 h[8]; uint4 u; } pk8;
        #pragma unroll
        for (int j = 0; j < 8; ++j) {
            int co = half*32 + g8*8 + j;
            float a = b1[co];
            #pragma unroll
            for (int t = 0; t < 9; ++t) a += w1[co*9 + t] * xv[t];
            pk8.h[j] = (_Float16)fmaxf(a, 0.f);
        }
        *(uint4*)&dst[g8*8] = pk8.u;
    }
}

// ---------------- fused conv2 + QKV GEMM: f1h -> (LDS feat) -> QT/KT/VH ----------------
__global__ __launch_bounds__(256) void conv2qkv_kernel(float* __restrict__ ws)
{
    __shared__ __align__(16) char fT[16384];   // [64 t][128 k] f16, byte ^ ((t&7)<<4)

    int bid = blockIdx.x;            // 2b * 144
    int b   = bid / 144;
    int tile = bid % 144;
    int tid = threadIdx.x;
    int lane = tid & 63, w = tid >> 6;
    int lr = lane & 15, lk = lane >> 4;

    // zero the split-K counters (ordering vs attn guaranteed by kernel boundary)
    if (bid == 0 && tid < 288) ((int*)(ws + OFF_CNT))[tid] = 0;

    const _Float16* Wc  = (const _Float16*)(ws + OFF_W2T);   // [64][576]
    const float* b2f = ws + OFF_B2;

    int t = tile*64 + w*16 + lr;
    int h = t / 96, wc = t % 96;

    half8 z8;
    #pragma unroll
    for (int i = 0; i < 8; ++i) z8[i] = (_Float16)0.f;

    // ---- phase 1: conv2 for n = 0,1 ----
    #pragma unroll
    for (int n = 0; n < 2; ++n) {
        const _Float16* f1h = (const _Float16*)(ws + OFF_F1) + (size_t)(b*2 + n)*TOK*64;
        f32x4 acc[4];
        #pragma unroll
        for (int cs = 0; cs < 4; ++cs) {
            float bv = b2f[cs*16 + lr];
            acc[cs] = (f32x4){bv, bv, bv, bv};
        }
        #pragma unroll
        for (int ch = 0; ch < 18; ++ch) {
            int k = ch*32 + lk*8;
            int tap = k >> 6, ci = k & 63;
            int dh = tap / 3, dw = tap % 3;
            int r = h + dh - 1, c = wc + dw - 1;
            half8 af = z8;
            if ((unsigned)r < 96u && (unsigned)c < 96u)
                af = *(const half8*)&f1h[(size_t)(r*96 + c)*64 + ci];
            #pragma unroll
            for (int cs = 0; cs < 4; ++cs) {
                half8 bfr = *(const half8*)&Wc[(size_t)(cs*16 + lr)*576 + k];
                acc[cs] = __builtin_amdgcn_mfma_f32_16x16x32_f16(af, bfr, acc[cs], 0, 0, 0);
            }
        }
        #pragma unroll
        for (int cs = 0; cs < 4; ++cs)
            #pragma unroll
            for (int r = 0; r < 4; ++r) {
                int tl = w*16 + 4*lk + r;
                int off = tl*256 + (n*64 + cs*16 + lr)*2;
                *(_Float16*)(fT + (off ^ ((tl&7)<<4))) =
                    (_Float16)fmaxf(acc[cs][r], 0.f);
            }
    }
    __syncthreads();

    // ---- phase 2: qkv GEMM (B-frags from LDS) ----
    const _Float16* W  = (const _Float16*)(ws + OFF_WCAT);
    const float* bc = ws + OFF_BCAT;
    _Float16* QT = (_Float16*)(ws + OFF_QT) + (size_t)b*TOK*64;
    _Float16* KT = (_Float16*)(ws + OFF_KT) + (size_t)b*TOK*64;
    _Float16* VH = (_Float16*)(ws + OFF_VH) + (size_t)b*64*TOK;

    half8 bf[4][4];
    #pragma unroll
    for (int tt = 0; tt < 4; ++tt)
        #pragma unroll
        for (int kc = 0; kc < 4; ++kc) {
            int tl = tt*16 + lr;
            bf[tt][kc] = *(const half8*)(fT + ((tl*256 + kc*64 + lk*16) ^ ((tl&7)<<4)));
        }

    half8 af3[3][4];
    #pragma unroll
    for (int i = 0; i < 3; ++i)
        #pragma unroll
        for (int kc = 0; kc < 4; ++kc)
            af3[i][kc] = *(const half8*)&W[(size_t)((w*3 + i)*16 + lr)*128 + kc*32 + lk*8];

    #pragma unroll
    for (int i = 0; i < 3; ++i) {
        int ot = w*3 + i;
        f32x4 a[4];
        #pragma unroll
        for (int r = 0; r < 4; ++r) {
            float bv = bc[ot*16 + 4*lk + r];
            #pragma unroll
            for (int tt = 0; tt < 4; ++tt) a[tt][r] = bv;
        }
        #pragma unroll
        for (int kc = 0; kc < 4; ++kc)
            #pragma unroll
            for (int tt = 0; tt < 4; ++tt)
                a[tt] = __builtin_amdgcn_mfma_f32_16x16x32_f16(af3[i][kc], bf[tt][kc], a[tt], 0, 0, 0);
        #pragma unroll
        for (int tt = 0; tt < 4; ++tt) {
            int tg = tile*64 + tt*16 + lr;
            if (ot < 4) {
                union { _Float16 h[4]; uint2 u; } p;
                #pragma unroll
                for (int r = 0; r < 4; ++r) p.h[r] = (_Float16)a[tt][r];
                *(uint2*)&QT[(size_t)tg*64 + ot*16 + 4*lk] = p.u;
            } else if (ot < 8) {
                union { _Float16 h[4]; uint2 u; } p;
                #pragma unroll
                for (int r = 0; r < 4; ++r) p.h[r] = (_Float16)a[tt][r];
                *(uint2*)&KT[(size_t)tg*64 + (ot-4)*16 + 4*lk] = p.u;
            } else {
                #pragma unroll
                for (int r = 0; r < 4; ++r)
                    VH[(size_t)((ot-8)*16 + 4*lk + r)*TOK + tg] = (_Float16)a[tt][r];
            }
        }
    }
}

// ---------------- flash attention partial + fused split-K recombine ----------------
// grid = 2b x 72qt x KSPLIT; 512 thr. Last-finishing block per (b,qt) recombines.
__global__ __launch_bounds__(512, 6) void attn_kernel(float* __restrict__ ws,
                                                      float* __restrict__ out)
{
    __shared__ __align__(16) char smem[32768];   // K0|K1|V0|V1; epilogue f32 [64][68]
    float* ldsf = (float*)smem;

    int bid = blockIdx.x;       // 2 * 72 * KSPLIT = 720
    int b   = bid / (72*KSPLIT);
    int rem = bid % (72*KSPLIT);
    int qt  = rem / KSPLIT;
    int ks  = rem % KSPLIT;
    int tid = threadIdx.x;
    int lane = tid & 63, w = tid >> 6;          // 8 waves
    int wq = w & 3;
    int q0 = qt * 128;
    int lr = lane & 15;
    int lk = lane >> 4;

    int kb0 = (ks*144)/KSPLIT, kb1 = ((ks+1)*144)/KSPLIT;   // 64-wide kt tiles
    int nit = kb1 - kb0;
    int slab = b*KSPLIT + ks;

    const _Float16* Qt = (const _Float16*)(ws + OFF_QT) + (size_t)b*TOK*64;
    const _Float16* Kt = (const _Float16*)(ws + OFF_KT) + (size_t)b*TOK*64;
    const _Float16* Vh = (const _Float16*)(ws + OFF_VH) + (size_t)b*64*TOK;
    float* part = part_base(ws, slab);
    float* ml   = ws + OFF_ML2 + (size_t)slab*2*TOK;

    half8 qB[2];
    #pragma unroll
    for (int ch = 0; ch < 2; ++ch)
        qB[ch] = *(const half8*)&Qt[(size_t)(q0 + w*16 + lr)*64 + ch*32 + lk*8];

    const f32x4 Z4 = (f32x4){0.f, 0.f, 0.f, 0.f};
    half8 ones;
    #pragma unroll
    for (int i = 0; i < 8; ++i) ones[i] = (_Float16)1.0f;

    f32x4 O[4];
    #pragma unroll
    for (int cs = 0; cs < 4; ++cs) O[cs] = Z4;
    f32x4 lacc = Z4;
    float mM = -INFINITY;

    int segl = ((lane & 7) ^ ((lane >> 3) & 7)) * 8;
    int rrow = w*8 + (lane >> 3);
    unsigned kOff = (unsigned)(kb0*64 + rrow)*64u + (unsigned)segl;
    unsigned vOff = (unsigned)rrow*(unsigned)TOK + (unsigned)(kb0*64) + (unsigned)segl;
    unsigned wbase = (unsigned)(w * 1024);

    GLOAD_LDS(Kt + kOff, smem +         wbase);
    GLOAD_LDS(Vh + vOff, smem + 16384 + wbase);
    asm volatile("s_waitcnt vmcnt(0)" ::: "memory");
    __builtin_amdgcn_s_barrier();

    for (int it = 0; it < nit; ++it) {
        char* sKb = smem +         (it & 1) * 8192;
        char* sVb = smem + 16384 + (it & 1) * 8192;

        if (it + 1 < nit) {
            unsigned bufo = (unsigned)(((it + 1) & 1) * 8192) + wbase;
            GLOAD_LDS(Kt + kOff + (unsigned)(it + 1) * 4096u, smem + bufo);
            GLOAD_LDS(Vh + vOff + (unsigned)(it + 1) * 64u,   smem + 16384 + bufo);
        }

        f32x4 S[4];
        __builtin_amdgcn_s_setprio(1);
        #pragma unroll
        for (int st = 0; st < 4; ++st) {
            int t = st*16 + lr;
            half8 kA0 = *(const half8*)(sKb + ((t*128 +      lk*16) ^ ((t&7)<<4)));
            half8 kA1 = *(const half8*)(sKb + ((t*128 + 64 + lk*16) ^ ((t&7)<<4)));
            f32x4 s = __builtin_amdgcn_mfma_f32_16x16x32_f16(kA0, qB[0], Z4, 0, 0, 0);
            S[st]   = __builtin_amdgcn_mfma_f32_16x16x32_f16(kA1, qB[1], s,  0, 0, 0);
        }
        __builtin_amdgcn_s_setprio(0);

        float a0 = fmaxf(fmaxf(S[0][0], S[0][1]), S[0][2]);
        float a1 = fmaxf(fmaxf(S[0][3], S[1][0]), S[1][1]);
        float a2 = fmaxf(fmaxf(S[1][2], S[1][3]), S[2][0]);
        float a3 = fmaxf(fmaxf(S[2][1], S[2][2]), S[2][3]);
        float a4 = fmaxf(fmaxf(S[3][0], S[3][1]), S[3][2]);
        float pm = fmaxf(fmaxf(fmaxf(a0, a1), a2),
                         fmaxf(fmaxf(a3, a4), S[3][3]));
        pm = fmaxf(pm, __shfl_xor(pm, 16));
        pm = fmaxf(pm, __shfl_xor(pm, 32));

        if (__any(pm > mM + 8.0f)) {
            float mn = fmaxf(mM, pm);
            float fs = exp2f(mM - mn);
            mM = mn;
            #pragma unroll
            for (int cs = 0; cs < 4; ++cs)
                #pragma unroll
                for (int r = 0; r < 4; ++r) O[cs][r] *= fs;
            #pragma unroll
            for (int r = 0; r < 4; ++r) lacc[r] *= fs;
        }

        #pragma unroll
        for (int st = 0; st < 4; ++st)
            #pragma unroll
            for (int r = 0; r < 4; ++r)
                S[st][r] = exp2f(S[st][r] - mM);

        unsigned int pk2[4][2];
        #pragma unroll
        for (int st = 0; st < 4; ++st) {
            pk2[st][0] = __builtin_bit_cast(unsigned int,
                             __builtin_amdgcn_cvt_pkrtz(S[st][0], S[st][1]));
            pk2[st][1] = __builtin_bit_cast(unsigned int,
                             __builtin_amdgcn_cvt_pkrtz(S[st][2], S[st][3]));
        }

        int srcA = lr + 32*(lk & 1);
        int sel  = lk >> 1;
        __builtin_amdgcn_s_setprio(1);
        #pragma unroll
        for (int ch2 = 0; ch2 < 2; ++ch2) {
            union { unsigned int u[4]; half8 h; } pb;
            #pragma unroll
            for (int w2 = 0; w2 < 4; ++w2) {
                int src = srcA + 16*(w2 >> 1);
                int lo = __shfl((int)pk2[ch2*2 + 0][w2 & 1], src);
                int hi = __shfl((int)pk2[ch2*2 + 1][w2 & 1], src);
                pb.u[w2] = (unsigned int)(sel ? hi : lo);
            }
            lacc = __builtin_amdgcn_mfma_f32_16x16x32_f16(ones, pb.h, lacc, 0, 0, 0);
            #pragma unroll
            for (int cs = 0; cs < 4; ++cs) {
                int crow = cs*16 + lr;
                half8 vA = *(const half8*)(sVb + ((crow*128 + ch2*64 + lk*16) ^ ((crow&7)<<4)));
                O[cs] = __builtin_amdgcn_mfma_f32_16x16x32_f16(vA, pb.h, O[cs], 0, 0, 0);
            }
        }
        __builtin_amdgcn_s_setprio(0);

        asm volatile("s_waitcnt vmcnt(0)" ::: "memory");
        __builtin_amdgcn_s_barrier();
    }

    if (lk == 0) {
        ml[q0 + w*16 + lr]       = mM;
        ml[TOK + q0 + w*16 + lr] = lacc[0];
    }

    // ---- epilogue: two 64-q halves through ldsf ----
    #pragma unroll
    for (int h = 0; h < 2; ++h) {
        if ((w >> 2) == h) {
            #pragma unroll
            for (int cs = 0; cs < 4; ++cs)
                #pragma unroll
                for (int r = 0; r < 4; ++r)
                    ldsf[(cs*16 + 4*lk + r)*68 + wq*16 + lr] = O[cs][r];
        }
        __syncthreads();
        int c = tid >> 3, qs = (tid & 7) * 8;
        const float* srcr = &ldsf[c*68 + qs];
        float* dstr = &part[(size_t)c*TOK + q0 + h*64 + qs];
        *(float4*)&dstr[0] = *(const float4*)&srcr[0];
        *(float4*)&dstr[4] = *(const float4*)&srcr[4];
        __syncthreads();
    }

    // ---- split-K completion: last block per (b,qt) recombines its 128 tokens ----
    __threadfence();                       // release: partial+ml visible device-wide
    __syncthreads();                       // all threads' fences done
    volatile int* sOld = (volatile int*)smem;
    if (tid == 0)
        *sOld = atomicAdd((int*)(ws + OFF_CNT) + (b*72 + qt), 1);
    __syncthreads();
    if (*sOld == KSPLIT - 1) {
        __threadfence();                   // acquire: other slabs' writes visible
        const float* mlp = ws + OFF_ML2;
        int t  = q0 + (tid & 31) * 4;      // 32 token-quads
        int cb = (tid >> 5) * 4;           // 16 channel groups of 4

        float4 m4[KSPLIT], l4[KSPLIT];
        float4 M = {-INFINITY, -INFINITY, -INFINITY, -INFINITY};
        #pragma unroll
        for (int s = 0; s < KSPLIT; ++s) {
            int sl = b*KSPLIT + s;
            m4[s] = *(const float4*)&mlp[(size_t)sl*2*TOK + t];
            l4[s] = *(const float4*)&mlp[(size_t)sl*2*TOK + TOK + t];
            M.x = fmaxf(M.x, m4[s].x); M.y = fmaxf(M.y, m4[s].y);
            M.z = fmaxf(M.z, m4[s].z); M.w = fmaxf(M.w, m4[s].w);
        }
        float4 wgt[KSPLIT];
        float4 den = {0.f, 0.f, 0.f, 0.f};
        #pragma unroll
        for (int s = 0; s < KSPLIT; ++s) {
            wgt[s].x = exp2f(m4[s].x - M.x); wgt[s].y = exp2f(m4[s].y - M.y);
            wgt[s].z = exp2f(m4[s].z - M.z); wgt[s].w = exp2f(m4[s].w - M.w);
            den.x += l4[s].x * wgt[s].x; den.y += l4[s].y * wgt[s].y;
            den.z += l4[s].z * wgt[s].z; den.w += l4[s].w * wgt[s].w;
        }
        float4 inv = {1.f/den.x, 1.f/den.y, 1.f/den.z, 1.f/den.w};
        #pragma unroll
        for (int cc = 0; cc < 4; ++cc) {
            int c = cb + cc;
            float4 acc = {0.f, 0.f, 0.f, 0.f};
            #pragma unroll
            for (int s = 0; s < KSPLIT; ++s) {
                const float* pp = part_base_c(ws, b*KSPLIT + s);
                float4 p4 = *(const float4*)&pp[(size_t)c*TOK + t];
                acc.x += p4.x * wgt[s].x; acc.y += p4.y * wgt[s].y;
                acc.z += p4.z * wgt[s].z; acc.w += p4.w * wgt[s].w;
            }
            float4 o4 = {acc.x*inv.x, acc.y*inv.y, acc.z*inv.z, acc.w*inv.w};
            *(float4*)&out[(size_t)(b*64 + c)*TOK + t] = o4;
        }
    }
}

extern "C" void kernel_launch(void* const* d_in, const int* in_sizes, int n_in,
                              void* d_out, int out_size, void* d_ws, size_t ws_size,
                              hipStream_t stream)
{
    const float* frames = (const float*)d_in[0];
    const float* w1 = (const float*)d_in[1];
    const float* b1 = (const float*)d_in[2];
    const float* w2 = (const float*)d_in[3];
    const float* b2 = (const float*)d_in[4];
    const float* qw = (const float*)d_in[5];
    const float* qb = (const float*)d_in[6];
    const float* kw = (const float*)d_in[7];
    const float* kb = (const float*)d_in[8];
    const float* vw = (const float*)d_in[9];
    const float* vb = (const float*)d_in[10];
    float* ws = (float*)d_ws;
    float* out = (float*)d_out;

    hipLaunchKernelGGL(conv1_kernel, dim3(288), dim3(256), 0, stream,
                       frames, w1, b1, w2, b2, qw, qb, kw, kb, vw, vb, ws);
    hipLaunchKernelGGL(conv2qkv_kernel, dim3(288), dim3(256), 0, stream, ws);
    hipLaunchKernelGGL(attn_kernel, dim3(2*72*KSPLIT), dim3(512), 0, stream, ws, out);
}

// Round 23
// 161.634 us; speedup vs baseline: 2.4729x; 2.4729x over previous
//
#include <hip/hip_runtime.h>
#include <hip/hip_bf16.h>

#define TOK 9216   // 96*96 tokens per image
#define KSPLIT 5

typedef _Float16 half8 __attribute__((ext_vector_type(8)));
typedef float f32x4 __attribute__((ext_vector_type(4)));

// global_load_lds: 16B per lane, linear LDS dest (wave-uniform base + lane*16)
#define GLOAD_LDS(g, l) \
    __builtin_amdgcn_global_load_lds((const __attribute__((address_space(1))) void*)(g), \
                                     (__attribute__((address_space(3))) void*)(l), 16, 0, 0)

#define QSCALE 0.18033688011112042f   // 0.125 * log2(e); softmax runs in exp2 domain

// ---------------- workspace layout (in floats) ----------------
// [0, 2359296)        F1: conv1 out f16 [img][t][64]   (dead after conv2qkv ph1)
// [2359296, 4718592)  FEAT region (feat LDS-internal; dead)
// [4718592, 6488064)  QT | KT | VH  (f16; written conv2qkv ph2, read attn)
// [0, 4718592)        slabs 0-7 (attn partials; F1+FEAT dead by then)
// [6488064, 7667712)  slabs 8-9
// [7667712, 7852032)  ML2
// [8257536, ...)      weights (W2T/B2/WCAT/BCAT)
#define OFF_F1   0u
#define SZ_F1    (4u*64u*TOK)            // 2359296
#define OFF_FEAT (OFF_F1 + SZ_F1)
#define SZ_FEAT  (2u*128u*TOK)           // 2359296
#define OFF_W1   (OFF_FEAT + SZ_FEAT + 3u*2u*64u*TOK)   // 8257536
#define OFF_B1   (OFF_W1 + 576u)
#define OFF_W2T  (OFF_B1 + 64u)          // WCONV f16 [64 co][576 k], k=tap*64+ci
#define OFF_B2   (OFF_W2T + 36864u)
#define OFF_WCAT (OFF_B2 + 64u)          // [192][128] f16, col k = n*64+c (q rows scaled)
#define OFF_BCAT (OFF_WCAT + 24576u)     // [192] f32 (qb scaled)

// QKV region disjoint from F1 (r21 race fix).
#define OFF_QT   4718592u                // [b][t][64] f16, scale folded
#define OFF_KT   5308416u                // [b][t][64] f16
#define OFF_VH   5898240u                // [b][64][t] f16, ends at 6488064

#define OFF_ML2  (OFF_FEAT + 9u*589824u) // 7667712: [slab][2 (m,l)][TOK] f32

__device__ __forceinline__ const float* part_base_c(const float* ws, int slab) {
    return ws + (slab < 8 ? (unsigned)slab * 589824u
                          : 6488064u + (unsigned)(slab - 8) * 589824u);
}
__device__ __forceinline__ float* part_base(float* ws, int slab) {
    return ws + (slab < 8 ? (unsigned)slab * 589824u
                          : 6488064u + (unsigned)(slab - 8) * 589824u);
}

// ---------------- conv1 (+ merged weight prep): 1->64 ch, 3x3, relu; f16 channel-last ----
// grid 576x256: 4 threads per pixel (16 channels each).
__global__ __launch_bounds__(256) void conv1_kernel(
    const float* __restrict__ x,
    const float* __restrict__ w1, const float* __restrict__ b1,
    const float* __restrict__ w2, const float* __restrict__ b2,
    const float* __restrict__ qw, const float* __restrict__ qb,
    const float* __restrict__ kw, const float* __restrict__ kb,
    const float* __restrict__ vw, const float* __restrict__ vb,
    float* __restrict__ ws)
{
    int gid = blockIdx.x * 256 + threadIdx.x;   // 576*256 = 147456

    // ---- merged prep (each element written by exactly one thread) ----
    if (gid < 64) ws[OFF_B2 + gid] = b2[gid];
    if (gid < 36864) {   // WCONV f16: [co][tap*64+ci] <- w2[co][ci][tap]
        int co = gid / 576; int rem = gid % 576;
        int ci = rem / 9;  int tp = rem % 9;
        ((_Float16*)(ws + OFF_W2T))[co*576 + tp*64 + ci] = (_Float16)w2[gid];
    }
    if (gid < 24576) {   // WCAT f16, col k = n*64+c <- source col c*2+n; q rows scaled
        int o = gid >> 7; int kidx = gid & 127;
        int n = kidx >> 6, c = kidx & 63;
        int sc = c*2 + n;
        float v;
        if (o < 64)       v = qw[o*128 + sc] * QSCALE;
        else if (o < 128) v = kw[(o-64)*128 + sc];
        else              v = vw[(o-128)*128 + sc];
        ((_Float16*)(ws + OFF_WCAT))[gid] = (_Float16)v;
    }
    if (gid < 192) {
        float v;
        if (gid < 64)       v = qb[gid] * QSCALE;
        else if (gid < 128) v = kb[gid-64];
        else                v = vb[gid-128];
        ws[OFF_BCAT + gid] = v;
    }

    // ---- conv1: 4 threads/pixel ----
    _Float16* f1h = (_Float16*)(ws + OFF_F1);
    int px = gid >> 2, q4 = gid & 3;
    int img = px / TOK;
    int p   = px % TOK;
    int h = p / 96, w = p % 96;
    float xv[9];
    #pragma unroll
    for (int dh = 0; dh < 3; ++dh)
        #pragma unroll
        for (int dw = 0; dw < 3; ++dw) {
            int r = h + dh - 1, c = w + dw - 1;
            bool ok = (r >= 0) && (r < 96) && (c >= 0) && (c < 96);
            xv[dh*3 + dw] = ok ? x[img*TOK + r*96 + c] : 0.f;
        }
    _Float16* dst = f1h + (size_t)px * 64 + q4 * 16;
    #pragma unroll
    for (int g8 = 0; g8 < 2; ++g8) {
        union { _Float16 h[8]; uint4 u; } pk8;
        #pragma unroll
        for (int j = 0; j < 8; ++j) {
            int co = q4*16 + g8*8 + j;
            float a = b1[co];
            #pragma unroll
            for (int t = 0; t < 9; ++t) a += w1[co*9 + t] * xv[t];
            pk8.h[j] = (_Float16)fmaxf(a, 0.f);
        }
        *(uint4*)&dst[g8*8] = pk8.u;
    }
}

// ---------------- fused conv2 + QKV GEMM (8 waves): f1h -> (LDS feat) -> QT/KT/VH ----
// grid = 2b x 144 token-tiles(64); 512 thr.
// Phase 1: wave w does frame n=w>>2, tokens (w&3)*16..+16 -> swizzled LDS [64 t][128 k].
// Phase 2: 48 (ot,tt) units distributed 6 per wave.
__global__ __launch_bounds__(512) void conv2qkv_kernel(float* __restrict__ ws)
{
    __shared__ __align__(16) char fT[16384];   // [64 t][128 k] f16, byte ^ ((t&7)<<4)

    int bid = blockIdx.x;            // 2b * 144
    int b   = bid / 144;
    int tile = bid % 144;
    int tid = threadIdx.x;
    int lane = tid & 63, w = tid >> 6;   // 8 waves
    int wq = w & 3, n = w >> 2;
    int lr = lane & 15, lk = lane >> 4;

    const _Float16* Wc  = (const _Float16*)(ws + OFF_W2T);   // [64][576]
    const float* b2f = ws + OFF_B2;

    half8 z8;
    #pragma unroll
    for (int i = 0; i < 8; ++i) z8[i] = (_Float16)0.f;

    // ---- phase 1: conv2, this wave's frame + 16-token row ----
    {
        const _Float16* f1h = (const _Float16*)(ws + OFF_F1) + (size_t)(b*2 + n)*TOK*64;
        int t = tile*64 + wq*16 + lr;
        int h = t / 96, wc = t % 96;
        f32x4 acc[4];
        #pragma unroll
        for (int cs = 0; cs < 4; ++cs) {
            float bv = b2f[cs*16 + lr];
            acc[cs] = (f32x4){bv, bv, bv, bv};
        }
        #pragma unroll
        for (int ch = 0; ch < 18; ++ch) {
            int k = ch*32 + lk*8;
            int tap = k >> 6, ci = k & 63;
            int dh = tap / 3, dw = tap % 3;
            int r = h + dh - 1, c = wc + dw - 1;
            half8 af = z8;
            if ((unsigned)r < 96u && (unsigned)c < 96u)
                af = *(const half8*)&f1h[(size_t)(r*96 + c)*64 + ci];
            #pragma unroll
            for (int cs = 0; cs < 4; ++cs) {
                half8 bfr = *(const half8*)&Wc[(size_t)(cs*16 + lr)*576 + k];
                acc[cs] = __builtin_amdgcn_mfma_f32_16x16x32_f16(af, bfr, acc[cs], 0, 0, 0);
            }
        }
        #pragma unroll
        for (int cs = 0; cs < 4; ++cs)
            #pragma unroll
            for (int r = 0; r < 4; ++r) {
                int tl = wq*16 + 4*lk + r;
                int off = tl*256 + (n*64 + cs*16 + lr)*2;
                *(_Float16*)(fT + (off ^ ((tl&7)<<4))) =
                    (_Float16)fmaxf(acc[cs][r], 0.f);
            }
    }
    __syncthreads();

    // ---- phase 2: qkv GEMM, 6 units per wave ----
    const _Float16* W  = (const _Float16*)(ws + OFF_WCAT);
    const float* bc = ws + OFF_BCAT;
    _Float16* QT = (_Float16*)(ws + OFF_QT) + (size_t)b*TOK*64;
    _Float16* KT = (_Float16*)(ws + OFF_KT) + (size_t)b*TOK*64;
    _Float16* VH = (_Float16*)(ws + OFF_VH) + (size_t)b*64*TOK;

    #pragma unroll
    for (int j = 0; j < 6; ++j) {
        int u  = w*6 + j;
        int ot = u >> 2, tt = u & 3;
        int tl = tt*16 + lr;
        f32x4 a;
        #pragma unroll
        for (int r = 0; r < 4; ++r) a[r] = bc[ot*16 + 4*lk + r];
        #pragma unroll
        for (int kc = 0; kc < 4; ++kc) {
            half8 bfr = *(const half8*)(fT + ((tl*256 + kc*64 + lk*16) ^ ((tl&7)<<4)));
            half8 afr = *(const half8*)&W[(size_t)(ot*16 + lr)*128 + kc*32 + lk*8];
            a = __builtin_amdgcn_mfma_f32_16x16x32_f16(afr, bfr, a, 0, 0, 0);
        }
        int tg = tile*64 + tt*16 + lr;
        if (ot < 4) {
            union { _Float16 h[4]; uint2 u2; } p;
            #pragma unroll
            for (int r = 0; r < 4; ++r) p.h[r] = (_Float16)a[r];
            *(uint2*)&QT[(size_t)tg*64 + ot*16 + 4*lk] = p.u2;
        } else if (ot < 8) {
            union { _Float16 h[4]; uint2 u2; } p;
            #pragma unroll
            for (int r = 0; r < 4; ++r) p.h[r] = (_Float16)a[r];
            *(uint2*)&KT[(size_t)tg*64 + (ot-4)*16 + 4*lk] = p.u2;
        } else {
            #pragma unroll
            for (int r = 0; r < 4; ++r)
                VH[(size_t)((ot-8)*16 + 4*lk + r)*TOK + tg] = (_Float16)a[r];
        }
    }
}

// ---------------- flash attention partial: 8 waves x 128q, KVBLK=64 (frozen r19/r21) ----
__global__ __launch_bounds__(512, 6) void attn_kernel(float* __restrict__ ws)
{
    __shared__ __align__(16) char smem[32768];   // K0|K1|V0|V1 (4x8KB); epilogue f32 [64][68]
    float* ldsf = (float*)smem;

    int bid = blockIdx.x;       // 2 * 72 * KSPLIT = 720
    int b   = bid / (72*KSPLIT);
    int rem = bid % (72*KSPLIT);
    int qt  = rem / KSPLIT;
    int ks  = rem % KSPLIT;
    int tid = threadIdx.x;
    int lane = tid & 63, w = tid >> 6;          // 8 waves
    int wq = w & 3;
    int q0 = qt * 128;
    int lr = lane & 15;
    int lk = lane >> 4;

    int kb0 = (ks*144)/KSPLIT, kb1 = ((ks+1)*144)/KSPLIT;   // 64-wide kt tiles
    int nit = kb1 - kb0;
    int slab = b*KSPLIT + ks;

    const _Float16* Qt = (const _Float16*)(ws + OFF_QT) + (size_t)b*TOK*64;
    const _Float16* Kt = (const _Float16*)(ws + OFF_KT) + (size_t)b*TOK*64;
    const _Float16* Vh = (const _Float16*)(ws + OFF_VH) + (size_t)b*64*TOK;
    float* part = part_base(ws, slab);
    float* ml   = ws + OFF_ML2 + (size_t)slab*2*TOK;

    half8 qB[2];
    #pragma unroll
    for (int ch = 0; ch < 2; ++ch)
        qB[ch] = *(const half8*)&Qt[(size_t)(q0 + w*16 + lr)*64 + ch*32 + lk*8];

    const f32x4 Z4 = (f32x4){0.f, 0.f, 0.f, 0.f};
    half8 ones;
    #pragma unroll
    for (int i = 0; i < 8; ++i) ones[i] = (_Float16)1.0f;

    f32x4 O[4];
    #pragma unroll
    for (int cs = 0; cs < 4; ++cs) O[cs] = Z4;
    f32x4 lacc = Z4;
    float mM = -INFINITY;

    int segl = ((lane & 7) ^ ((lane >> 3) & 7)) * 8;
    int rrow = w*8 + (lane >> 3);
    unsigned kOff = (unsigned)(kb0*64 + rrow)*64u + (unsigned)segl;
    unsigned vOff = (unsigned)rrow*(unsigned)TOK + (unsigned)(kb0*64) + (unsigned)segl;
    unsigned wbase = (unsigned)(w * 1024);

    GLOAD_LDS(Kt + kOff, smem +         wbase);
    GLOAD_LDS(Vh + vOff, smem + 16384 + wbase);
    asm volatile("s_waitcnt vmcnt(0)" ::: "memory");
    __builtin_amdgcn_s_barrier();

    for (int it = 0; it < nit; ++it) {
        char* sKb = smem +         (it & 1) * 8192;
        char* sVb = smem + 16384 + (it & 1) * 8192;

        if (it + 1 < nit) {
            unsigned bufo = (unsigned)(((it + 1) & 1) * 8192) + wbase;
            GLOAD_LDS(Kt + kOff + (unsigned)(it + 1) * 4096u, smem + bufo);
            GLOAD_LDS(Vh + vOff + (unsigned)(it + 1) * 64u,   smem + 16384 + bufo);
        }

        f32x4 S[4];
        __builtin_amdgcn_s_setprio(1);
        #pragma unroll
        for (int st = 0; st < 4; ++st) {
            int t = st*16 + lr;
            half8 kA0 = *(const half8*)(sKb + ((t*128 +      lk*16) ^ ((t&7)<<4)));
            half8 kA1 = *(const half8*)(sKb + ((t*128 + 64 + lk*16) ^ ((t&7)<<4)));
            f32x4 s = __builtin_amdgcn_mfma_f32_16x16x32_f16(kA0, qB[0], Z4, 0, 0, 0);
            S[st]   = __builtin_amdgcn_mfma_f32_16x16x32_f16(kA1, qB[1], s,  0, 0, 0);
        }
        __builtin_amdgcn_s_setprio(0);

        float a0 = fmaxf(fmaxf(S[0][0], S[0][1]), S[0][2]);
        float a1 = fmaxf(fmaxf(S[0][3], S[1][0]), S[1][1]);
        float a2 = fmaxf(fmaxf(S[1][2], S[1][3]), S[2][0]);
        float a3 = fmaxf(fmaxf(S[2][1], S[2][2]), S[2][3]);
        float a4 = fmaxf(fmaxf(S[3][0], S[3][1]), S[3][2]);
        float pm = fmaxf(fmaxf(fmaxf(a0, a1), a2),
                         fmaxf(fmaxf(a3, a4), S[3][3]));
        pm = fmaxf(pm, __shfl_xor(pm, 16));
        pm = fmaxf(pm, __shfl_xor(pm, 32));

        if (__any(pm > mM + 8.0f)) {
            float mn = fmaxf(mM, pm);
            float fs = exp2f(mM - mn);
            mM = mn;
            #pragma unroll
            for (int cs = 0; cs < 4; ++cs)
                #pragma unroll
                for (int r = 0; r < 4; ++r) O[cs][r] *= fs;
            #pragma unroll
            for (int r = 0; r < 4; ++r) lacc[r] *= fs;
        }

        #pragma unroll
        for (int st = 0; st < 4; ++st)
            #pragma unroll
            for (int r = 0; r < 4; ++r)
                S[st][r] = exp2f(S[st][r] - mM);

        unsigned int pk2[4][2];
        #pragma unroll
        for (int st = 0; st < 4; ++st) {
            pk2[st][0] = __builtin_bit_cast(unsigned int,
                             __builtin_amdgcn_cvt_pkrtz(S[st][0], S[st][1]));
            pk2[st][1] = __builtin_bit_cast(unsigned int,
                             __builtin_amdgcn_cvt_pkrtz(S[st][2], S[st][3]));
        }

        int srcA = lr + 32*(lk & 1);
        int sel  = lk >> 1;
        __builtin_amdgcn_s_setprio(1);
        #pragma unroll
        for (int ch2 = 0; ch2 < 2; ++ch2) {
            union { unsigned int u[4]; half8 h; } pb;
            #pragma unroll
            for (int w2 = 0; w2 < 4; ++w2) {
                int src = srcA + 16*(w2 >> 1);
                int lo = __shfl((int)pk2[ch2*2 + 0][w2 & 1], src);
                int hi = __shfl((int)pk2[ch2*2 + 1][w2 & 1], src);
                pb.u[w2] = (unsigned int)(sel ? hi : lo);
            }
            lacc = __builtin_amdgcn_mfma_f32_16x16x32_f16(ones, pb.h, lacc, 0, 0, 0);
            #pragma unroll
            for (int cs = 0; cs < 4; ++cs) {
                int crow = cs*16 + lr;
                half8 vA = *(const half8*)(sVb + ((crow*128 + ch2*64 + lk*16) ^ ((crow&7)<<4)));
                O[cs] = __builtin_amdgcn_mfma_f32_16x16x32_f16(vA, pb.h, O[cs], 0, 0, 0);
            }
        }
        __builtin_amdgcn_s_setprio(0);

        asm volatile("s_waitcnt vmcnt(0)" ::: "memory");
        __builtin_amdgcn_s_barrier();
    }

    if (lk == 0) {
        ml[q0 + w*16 + lr]       = mM;
        ml[TOK + q0 + w*16 + lr] = lacc[0];
    }

    #pragma unroll
    for (int h = 0; h < 2; ++h) {
        if ((w >> 2) == h) {
            #pragma unroll
            for (int cs = 0; cs < 4; ++cs)
                #pragma unroll
                for (int r = 0; r < 4; ++r)
                    ldsf[(cs*16 + 4*lk + r)*68 + wq*16 + lr] = O[cs][r];
        }
        __syncthreads();
        int c = tid >> 3, qs = (tid & 7) * 8;
        const float* srcr = &ldsf[c*68 + qs];
        float* dstr = &part[(size_t)c*TOK + q0 + h*64 + qs];
        *(float4*)&dstr[0] = *(const float4*)&srcr[0];
        *(float4*)&dstr[4] = *(const float4*)&srcr[4];
        __syncthreads();
    }
}

// ---------------- recombine KV-split partials (exp2 domain, float4, 288 blocks) ----------------
__global__ __launch_bounds__(256) void recombine_kernel(
    const float* __restrict__ ws, float* __restrict__ out)
{
    int bid = blockIdx.x;                       // 288
    int b   = bid / 144;
    int g2  = (bid % 144) * 256 + threadIdx.x;  // 0..36863
    int cq  = g2 / 2304;                        // channel quad 0..15
    int t   = (g2 % 2304) * 4;
    const float* mlp = ws + OFF_ML2;

    float4 m4[KSPLIT], l4[KSPLIT];
    float4 M = {-INFINITY, -INFINITY, -INFINITY, -INFINITY};
    #pragma unroll
    for (int ks = 0; ks < KSPLIT; ++ks) {
        int slab = b*KSPLIT + ks;
        m4[ks] = *(const float4*)&mlp[(size_t)slab*2*TOK + t];
        l4[ks] = *(const float4*)&mlp[(size_t)slab*2*TOK + TOK + t];
        M.x = fmaxf(M.x, m4[ks].x); M.y = fmaxf(M.y, m4[ks].y);
        M.z = fmaxf(M.z, m4[ks].z); M.w = fmaxf(M.w, m4[ks].w);
    }
    float4 wgt[KSPLIT];
    float4 den = {0.f, 0.f, 0.f, 0.f};
    #pragma unroll
    for (int ks = 0; ks < KSPLIT; ++ks) {
        wgt[ks].x = exp2f(m4[ks].x - M.x); wgt[ks].y = exp2f(m4[ks].y - M.y);
        wgt[ks].z = exp2f(m4[ks].z - M.z); wgt[ks].w = exp2f(m4[ks].w - M.w);
        den.x += l4[ks].x * wgt[ks].x; den.y += l4[ks].y * wgt[ks].y;
        den.z += l4[ks].z * wgt[ks].z; den.w += l4[ks].w * wgt[ks].w;
    }
    float4 inv = {1.f/den.x, 1.f/den.y, 1.f/den.z, 1.f/den.w};
    #pragma unroll
    for (int cc = 0; cc < 4; ++cc) {
        int c = cq*4 + cc;
        float4 acc = {0.f, 0.f, 0.f, 0.f};
        #pragma unroll
        for (int ks = 0; ks < KSPLIT; ++ks) {
            const float* part = part_base_c(ws, b*KSPLIT + ks);
            float4 p4 = *(const float4*)&part[(size_t)c*TOK + t];
            acc.x += p4.x * wgt[ks].x; acc.y += p4.y * wgt[ks].y;
            acc.z += p4.z * wgt[ks].z; acc.w += p4.w * wgt[ks].w;
        }
        float4 o4 = {acc.x*inv.x, acc.y*inv.y, acc.z*inv.z, acc.w*inv.w};
        *(float4*)&out[(size_t)(b*64 + c)*TOK + t] = o4;
    }
}

extern "C" void kernel_launch(void* const* d_in, const int* in_sizes, int n_in,
                              void* d_out, int out_size, void* d_ws, size_t ws_size,
                              hipStream_t stream)
{
    const float* frames = (const float*)d_in[0];
    const float* w1 = (const float*)d_in[1];
    const float* b1 = (const float*)d_in[2];
    const float* w2 = (const float*)d_in[3];
    const float* b2 = (const float*)d_in[4];
    const float* qw = (const float*)d_in[5];
    const float* qb = (const float*)d_in[6];
    const float* kw = (const float*)d_in[7];
    const float* kb = (const float*)d_in[8];
    const float* vw = (const float*)d_in[9];
    const float* vb = (const float*)d_in[10];
    float* ws = (float*)d_ws;
    float* out = (float*)d_out;

    hipLaunchKernelGGL(conv1_kernel, dim3(576), dim3(256), 0, stream,
                       frames, w1, b1, w2, b2, qw, qb, kw, kb, vw, vb, ws);
    hipLaunchKernelGGL(conv2qkv_kernel, dim3(288), dim3(512), 0, stream, ws);
    hipLaunchKernelGGL(attn_kernel, dim3(2*72*KSPLIT), dim3(512), 0, stream, ws);
    hipLaunchKernelGGL(recombine_kernel, dim3(288), dim3(256), 0, stream, ws, out);
}

// Round 24
// 156.864 us; speedup vs baseline: 2.5481x; 1.0304x over previous
//
#include <hip/hip_runtime.h>
#include <hip/hip_bf16.h>

#define TOK 9216   // 96*96 tokens per image
#define KSPLIT 5

typedef _Float16 half8 __attribute__((ext_vector_type(8)));
typedef float f32x4 __attribute__((ext_vector_type(4)));

// global_load_lds: 16B per lane, linear LDS dest (wave-uniform base + lane*16)
#define GLOAD_LDS(g, l) \
    __builtin_amdgcn_global_load_lds((const __attribute__((address_space(1))) void*)(g), \
                                     (__attribute__((address_space(3))) void*)(l), 16, 0, 0)

#define QSCALE 0.18033688011112042f   // 0.125 * log2(e); softmax runs in exp2 domain

// ---------------- workspace layout (in floats) ----------------
// [0, 2359296)        F1: conv1 out f16 [img][t][64]   (dead after conv2qkv ph1)
// [2359296, 4718592)  FEAT region (feat LDS-internal; dead)
// [4718592, 6488064)  QT | KT | VH  (f16; written conv2qkv ph2, read attn)
// [0, 4718592)        slabs 0-7 (attn partials; F1+FEAT dead by then)
// [6488064, 7667712)  slabs 8-9
// [7667712, 7852032)  ML2
// [8257536, ...)      weights (W2T/B2/WCAT/BCAT)
#define OFF_F1   0u
#define SZ_F1    (4u*64u*TOK)            // 2359296
#define OFF_FEAT (OFF_F1 + SZ_F1)
#define SZ_FEAT  (2u*128u*TOK)           // 2359296
#define OFF_W1   (OFF_FEAT + SZ_FEAT + 3u*2u*64u*TOK)   // 8257536
#define OFF_B1   (OFF_W1 + 576u)
#define OFF_W2T  (OFF_B1 + 64u)          // WCONV f16 [64 co][576 k], k=tap*64+ci
#define OFF_B2   (OFF_W2T + 36864u)
#define OFF_WCAT (OFF_B2 + 64u)          // [192][128] f16, col k = n*64+c (q rows scaled)
#define OFF_BCAT (OFF_WCAT + 24576u)     // [192] f32 (qb scaled)

// QKV region disjoint from F1 (r21 race fix).
#define OFF_QT   4718592u                // [b][t][64] f16, scale folded
#define OFF_KT   5308416u                // [b][t][64] f16
#define OFF_VH   5898240u                // [b][64][t] f16, ends at 6488064

#define OFF_ML2  (OFF_FEAT + 9u*589824u) // 7667712: [slab][2 (m,l)][TOK] f32

__device__ __forceinline__ const float* part_base_c(const float* ws, int slab) {
    return ws + (slab < 8 ? (unsigned)slab * 589824u
                          : 6488064u + (unsigned)(slab - 8) * 589824u);
}
__device__ __forceinline__ float* part_base(float* ws, int slab) {
    return ws + (slab < 8 ? (unsigned)slab * 589824u
                          : 6488064u + (unsigned)(slab - 8) * 589824u);
}

// ---------------- conv1 (+ merged weight prep): 1->64 ch, 3x3, relu; f16 channel-last ----
// grid 288x256: 2 threads per pixel (32 channels each).
__global__ __launch_bounds__(256) void conv1_kernel(
    const float* __restrict__ x,
    const float* __restrict__ w1, const float* __restrict__ b1,
    const float* __restrict__ w2, const float* __restrict__ b2,
    const float* __restrict__ qw, const float* __restrict__ qb,
    const float* __restrict__ kw, const float* __restrict__ kb,
    const float* __restrict__ vw, const float* __restrict__ vb,
    float* __restrict__ ws)
{
    int gid = blockIdx.x * 256 + threadIdx.x;   // 288*256 = 73728

    // ---- merged prep (each element written by exactly one thread) ----
    if (gid < 64) ws[OFF_B2 + gid] = b2[gid];
    if (gid < 36864) {   // WCONV f16: [co][tap*64+ci] <- w2[co][ci][tap]
        int co = gid / 576; int rem = gid % 576;
        int ci = rem / 9;  int tp = rem % 9;
        ((_Float16*)(ws + OFF_W2T))[co*576 + tp*64 + ci] = (_Float16)w2[gid];
    }
    if (gid < 24576) {   // WCAT f16, col k = n*64+c <- source col c*2+n; q rows scaled
        int o = gid >> 7; int kidx = gid & 127;
        int n = kidx >> 6, c = kidx & 63;
        int sc = c*2 + n;
        float v;
        if (o < 64)       v = qw[o*128 + sc] * QSCALE;
        else if (o < 128) v = kw[(o-64)*128 + sc];
        else              v = vw[(o-128)*128 + sc];
        ((_Float16*)(ws + OFF_WCAT))[gid] = (_Float16)v;
    }
    if (gid < 192) {
        float v;
        if (gid < 64)       v = qb[gid] * QSCALE;
        else if (gid < 128) v = kb[gid-64];
        else                v = vb[gid-128];
        ws[OFF_BCAT + gid] = v;
    }

    // ---- conv1: 2 threads/pixel ----
    _Float16* f1h = (_Float16*)(ws + OFF_F1);
    int px = gid >> 1, half = gid & 1;
    int img = px / TOK;
    int p   = px % TOK;
    int h = p / 96, w = p % 96;
    float xv[9];
    #pragma unroll
    for (int dh = 0; dh < 3; ++dh)
        #pragma unroll
        for (int dw = 0; dw < 3; ++dw) {
            int r = h + dh - 1, c = w + dw - 1;
            bool ok = (r >= 0) && (r < 96) && (c >= 0) && (c < 96);
            xv[dh*3 + dw] = ok ? x[img*TOK + r*96 + c] : 0.f;
        }
    _Float16* dst = f1h + (size_t)px * 64 + half * 32;
    #pragma unroll
    for (int g8 = 0; g8 < 4; ++g8) {
        union { _Float16 h[8]; uint4 u; } pk8;
        #pragma unroll
        for (int j = 0; j < 8; ++j) {
            int co = half*32 + g8*8 + j;
            float a = b1[co];
            #pragma unroll
            for (int t = 0; t < 9; ++t) a += w1[co*9 + t] * xv[t];
            pk8.h[j] = (_Float16)fmaxf(a, 0.f);
        }
        *(uint4*)&dst[g8*8] = pk8.u;
    }
}

// ---------------- fused conv2 + QKV GEMM: f1h -> (LDS feat) -> QT/KT/VH ----------------
// grid = 2b x 144 token-tiles(64); 256 thr = 4 waves.
__global__ __launch_bounds__(256) void conv2qkv_kernel(float* __restrict__ ws)
{
    __shared__ __align__(16) char fT[16384];   // [64 t][128 k] f16, byte ^ ((t&7)<<4)

    int bid = blockIdx.x;            // 2b * 144
    int b   = bid / 144;
    int tile = bid % 144;
    int tid = threadIdx.x;
    int lane = tid & 63, w = tid >> 6;
    int lr = lane & 15, lk = lane >> 4;

    const _Float16* Wc  = (const _Float16*)(ws + OFF_W2T);   // [64][576]
    const float* b2f = ws + OFF_B2;

    int t = tile*64 + w*16 + lr;
    int h = t / 96, wc = t % 96;

    half8 z8;
    #pragma unroll
    for (int i = 0; i < 8; ++i) z8[i] = (_Float16)0.f;

    // ---- phase 1: conv2 for n = 0,1 ----
    #pragma unroll
    for (int n = 0; n < 2; ++n) {
        const _Float16* f1h = (const _Float16*)(ws + OFF_F1) + (size_t)(b*2 + n)*TOK*64;
        f32x4 acc[4];
        #pragma unroll
        for (int cs = 0; cs < 4; ++cs) {
            float bv = b2f[cs*16 + lr];
            acc[cs] = (f32x4){bv, bv, bv, bv};
        }
        #pragma unroll
        for (int ch = 0; ch < 18; ++ch) {
            int k = ch*32 + lk*8;
            int tap = k >> 6, ci = k & 63;
            int dh = tap / 3, dw = tap % 3;
            int r = h + dh - 1, c = wc + dw - 1;
            half8 af = z8;
            if ((unsigned)r < 96u && (unsigned)c < 96u)
                af = *(const half8*)&f1h[(size_t)(r*96 + c)*64 + ci];
            #pragma unroll
            for (int cs = 0; cs < 4; ++cs) {
                half8 bfr = *(const half8*)&Wc[(size_t)(cs*16 + lr)*576 + k];
                acc[cs] = __builtin_amdgcn_mfma_f32_16x16x32_f16(af, bfr, acc[cs], 0, 0, 0);
            }
        }
        #pragma unroll
        for (int cs = 0; cs < 4; ++cs)
            #pragma unroll
            for (int r = 0; r < 4; ++r) {
                int tl = w*16 + 4*lk + r;
                int off = tl*256 + (n*64 + cs*16 + lr)*2;
                *(_Float16*)(fT + (off ^ ((tl&7)<<4))) =
                    (_Float16)fmaxf(acc[cs][r], 0.f);
            }
    }
    __syncthreads();

    // ---- phase 2: qkv GEMM (B-frags from LDS) ----
    const _Float16* W  = (const _Float16*)(ws + OFF_WCAT);
    const float* bc = ws + OFF_BCAT;
    _Float16* QT = (_Float16*)(ws + OFF_QT) + (size_t)b*TOK*64;
    _Float16* KT = (_Float16*)(ws + OFF_KT) + (size_t)b*TOK*64;
    _Float16* VH = (_Float16*)(ws + OFF_VH) + (size_t)b*64*TOK;

    half8 bf[4][4];
    #pragma unroll
    for (int tt = 0; tt < 4; ++tt)
        #pragma unroll
        for (int kc = 0; kc < 4; ++kc) {
            int tl = tt*16 + lr;
            bf[tt][kc] = *(const half8*)(fT + ((tl*256 + kc*64 + lk*16) ^ ((tl&7)<<4)));
        }

    half8 af3[3][4];
    #pragma unroll
    for (int i = 0; i < 3; ++i)
        #pragma unroll
        for (int kc = 0; kc < 4; ++kc)
            af3[i][kc] = *(const half8*)&W[(size_t)((w*3 + i)*16 + lr)*128 + kc*32 + lk*8];

    #pragma unroll
    for (int i = 0; i < 3; ++i) {
        int ot = w*3 + i;
        f32x4 a[4];
        #pragma unroll
        for (int r = 0; r < 4; ++r) {
            float bv = bc[ot*16 + 4*lk + r];
            #pragma unroll
            for (int tt = 0; tt < 4; ++tt) a[tt][r] = bv;
        }
        #pragma unroll
        for (int kc = 0; kc < 4; ++kc)
            #pragma unroll
            for (int tt = 0; tt < 4; ++tt)
                a[tt] = __builtin_amdgcn_mfma_f32_16x16x32_f16(af3[i][kc], bf[tt][kc], a[tt], 0, 0, 0);
        #pragma unroll
        for (int tt = 0; tt < 4; ++tt) {
            int tg = tile*64 + tt*16 + lr;
            if (ot < 4) {
                union { _Float16 h[4]; uint2 u; } p;
                #pragma unroll
                for (int r = 0; r < 4; ++r) p.h[r] = (_Float16)a[tt][r];
                *(uint2*)&QT[(size_t)tg*64 + ot*16 + 4*lk] = p.u;
            } else if (ot < 8) {
                union { _Float16 h[4]; uint2 u; } p;
                #pragma unroll
                for (int r = 0; r < 4; ++r) p.h[r] = (_Float16)a[tt][r];
                *(uint2*)&KT[(size_t)tg*64 + (ot-4)*16 + 4*lk] = p.u;
            } else {
                #pragma unroll
                for (int r = 0; r < 4; ++r)
                    VH[(size_t)((ot-8)*16 + 4*lk + r)*TOK + tg] = (_Float16)a[tt][r];
            }
        }
    }
}

// ---------------- flash attention partial: 8 waves x 128q, KVBLK=64 (frozen r19/r21) ----
__global__ __launch_bounds__(512, 6) void attn_kernel(float* __restrict__ ws)
{
    __shared__ __align__(16) char smem[32768];   // K0|K1|V0|V1 (4x8KB); epilogue f32 [64][68]
    float* ldsf = (float*)smem;

    int bid = blockIdx.x;       // 2 * 72 * KSPLIT = 720
    int b   = bid / (72*KSPLIT);
    int rem = bid % (72*KSPLIT);
    int qt  = rem / KSPLIT;
    int ks  = rem % KSPLIT;
    int tid = threadIdx.x;
    int lane = tid & 63, w = tid >> 6;          // 8 waves
    int wq = w & 3;
    int q0 = qt * 128;
    int lr = lane & 15;
    int lk = lane >> 4;

    int kb0 = (ks*144)/KSPLIT, kb1 = ((ks+1)*144)/KSPLIT;   // 64-wide kt tiles
    int nit = kb1 - kb0;
    int slab = b*KSPLIT + ks;

    const _Float16* Qt = (const _Float16*)(ws + OFF_QT) + (size_t)b*TOK*64;
    const _Float16* Kt = (const _Float16*)(ws + OFF_KT) + (size_t)b*TOK*64;
    const _Float16* Vh = (const _Float16*)(ws + OFF_VH) + (size_t)b*64*TOK;
    float* part = part_base(ws, slab);
    float* ml   = ws + OFF_ML2 + (size_t)slab*2*TOK;

    half8 qB[2];
    #pragma unroll
    for (int ch = 0; ch < 2; ++ch)
        qB[ch] = *(const half8*)&Qt[(size_t)(q0 + w*16 + lr)*64 + ch*32 + lk*8];

    const f32x4 Z4 = (f32x4){0.f, 0.f, 0.f, 0.f};
    half8 ones;
    #pragma unroll
    for (int i = 0; i < 8; ++i) ones[i] = (_Float16)1.0f;

    f32x4 O[4];
    #pragma unroll
    for (int cs = 0; cs < 4; ++cs) O[cs] = Z4;
    f32x4 lacc = Z4;
    float mM = -INFINITY;

    int segl = ((lane & 7) ^ ((lane >> 3) & 7)) * 8;
    int rrow = w*8 + (lane >> 3);
    unsigned kOff = (unsigned)(kb0*64 + rrow)*64u + (unsigned)segl;
    unsigned vOff = (unsigned)rrow*(unsigned)TOK + (unsigned)(kb0*64) + (unsigned)segl;
    unsigned wbase = (unsigned)(w * 1024);

    GLOAD_LDS(Kt + kOff, smem +         wbase);
    GLOAD_LDS(Vh + vOff, smem + 16384 + wbase);
    asm volatile("s_waitcnt vmcnt(0)" ::: "memory");
    __builtin_amdgcn_s_barrier();

    for (int it = 0; it < nit; ++it) {
        char* sKb = smem +         (it & 1) * 8192;
        char* sVb = smem + 16384 + (it & 1) * 8192;

        if (it + 1 < nit) {
            unsigned bufo = (unsigned)(((it + 1) & 1) * 8192) + wbase;
            GLOAD_LDS(Kt + kOff + (unsigned)(it + 1) * 4096u, smem + bufo);
            GLOAD_LDS(Vh + vOff + (unsigned)(it + 1) * 64u,   smem + 16384 + bufo);
        }

        f32x4 S[4];
        __builtin_amdgcn_s_setprio(1);
        #pragma unroll
        for (int st = 0; st < 4; ++st) {
            int t = st*16 + lr;
            half8 kA0 = *(const half8*)(sKb + ((t*128 +      lk*16) ^ ((t&7)<<4)));
            half8 kA1 = *(const half8*)(sKb + ((t*128 + 64 + lk*16) ^ ((t&7)<<4)));
            f32x4 s = __builtin_amdgcn_mfma_f32_16x16x32_f16(kA0, qB[0], Z4, 0, 0, 0);
            S[st]   = __builtin_amdgcn_mfma_f32_16x16x32_f16(kA1, qB[1], s,  0, 0, 0);
        }
        __builtin_amdgcn_s_setprio(0);

        float a0 = fmaxf(fmaxf(S[0][0], S[0][1]), S[0][2]);
        float a1 = fmaxf(fmaxf(S[0][3], S[1][0]), S[1][1]);
        float a2 = fmaxf(fmaxf(S[1][2], S[1][3]), S[2][0]);
        float a3 = fmaxf(fmaxf(S[2][1], S[2][2]), S[2][3]);
        float a4 = fmaxf(fmaxf(S[3][0], S[3][1]), S[3][2]);
        float pm = fmaxf(fmaxf(fmaxf(a0, a1), a2),
                         fmaxf(fmaxf(a3, a4), S[3][3]));
        pm = fmaxf(pm, __shfl_xor(pm, 16));
        pm = fmaxf(pm, __shfl_xor(pm, 32));

        if (__any(pm > mM + 8.0f)) {
            float mn = fmaxf(mM, pm);
            float fs = exp2f(mM - mn);
            mM = mn;
            #pragma unroll
            for (int cs = 0; cs < 4; ++cs)
                #pragma unroll
                for (int r = 0; r < 4; ++r) O[cs][r] *= fs;
            #pragma unroll
            for (int r = 0; r < 4; ++r) lacc[r] *= fs;
        }

        #pragma unroll
        for (int st = 0; st < 4; ++st)
            #pragma unroll
            for (int r = 0; r < 4; ++r)
                S[st][r] = exp2f(S[st][r] - mM);

        unsigned int pk2[4][2];
        #pragma unroll
        for (int st = 0; st < 4; ++st) {
            pk2[st][0] = __builtin_bit_cast(unsigned int,
                             __builtin_amdgcn_cvt_pkrtz(S[st][0], S[st][1]));
            pk2[st][1] = __builtin_bit_cast(unsigned int,
                             __builtin_amdgcn_cvt_pkrtz(S[st][2], S[st][3]));
        }

        int srcA = lr + 32*(lk & 1);
        int sel  = lk >> 1;
        __builtin_amdgcn_s_setprio(1);
        #pragma unroll
        for (int ch2 = 0; ch2 < 2; ++ch2) {
            union { unsigned int u[4]; half8 h; } pb;
            #pragma unroll
            for (int w2 = 0; w2 < 4; ++w2) {
                int src = srcA + 16*(w2 >> 1);
                int lo = __shfl((int)pk2[ch2*2 + 0][w2 & 1], src);
                int hi = __shfl((int)pk2[ch2*2 + 1][w2 & 1], src);
                pb.u[w2] = (unsigned int)(sel ? hi : lo);
            }
            lacc = __builtin_amdgcn_mfma_f32_16x16x32_f16(ones, pb.h, lacc, 0, 0, 0);
            #pragma unroll
            for (int cs = 0; cs < 4; ++cs) {
                int crow = cs*16 + lr;
                half8 vA = *(const half8*)(sVb + ((crow*128 + ch2*64 + lk*16) ^ ((crow&7)<<4)));
                O[cs] = __builtin_amdgcn_mfma_f32_16x16x32_f16(vA, pb.h, O[cs], 0, 0, 0);
            }
        }
        __builtin_amdgcn_s_setprio(0);

        asm volatile("s_waitcnt vmcnt(0)" ::: "memory");
        __builtin_amdgcn_s_barrier();
    }

    if (lk == 0) {
        ml[q0 + w*16 + lr]       = mM;
        ml[TOK + q0 + w*16 + lr] = lacc[0];
    }

    #pragma unroll
    for (int h = 0; h < 2; ++h) {
        if ((w >> 2) == h) {
            #pragma unroll
            for (int cs = 0; cs < 4; ++cs)
                #pragma unroll
                for (int r = 0; r < 4; ++r)
                    ldsf[(cs*16 + 4*lk + r)*68 + wq*16 + lr] = O[cs][r];
        }
        __syncthreads();
        int c = tid >> 3, qs = (tid & 7) * 8;
        const float* srcr = &ldsf[c*68 + qs];
        float* dstr = &part[(size_t)c*TOK + q0 + h*64 + qs];
        *(float4*)&dstr[0] = *(const float4*)&srcr[0];
        *(float4*)&dstr[4] = *(const float4*)&srcr[4];
        __syncthreads();
    }
}

// ---------------- recombine KV-split partials (exp2 domain, float4, 288 blocks) ----------------
__global__ __launch_bounds__(256) void recombine_kernel(
    const float* __restrict__ ws, float* __restrict__ out)
{
    int bid = blockIdx.x;                       // 288
    int b   = bid / 144;
    int g2  = (bid % 144) * 256 + threadIdx.x;  // 0..36863
    int cq  = g2 / 2304;                        // channel quad 0..15
    int t   = (g2 % 2304) * 4;
    const float* mlp = ws + OFF_ML2;

    float4 m4[KSPLIT], l4[KSPLIT];
    float4 M = {-INFINITY, -INFINITY, -INFINITY, -INFINITY};
    #pragma unroll
    for (int ks = 0; ks < KSPLIT; ++ks) {
        int slab = b*KSPLIT + ks;
        m4[ks] = *(const float4*)&mlp[(size_t)slab*2*TOK + t];
        l4[ks] = *(const float4*)&mlp[(size_t)slab*2*TOK + TOK + t];
        M.x = fmaxf(M.x, m4[ks].x); M.y = fmaxf(M.y, m4[ks].y);
        M.z = fmaxf(M.z, m4[ks].z); M.w = fmaxf(M.w, m4[ks].w);
    }
    float4 wgt[KSPLIT];
    float4 den = {0.f, 0.f, 0.f, 0.f};
    #pragma unroll
    for (int ks = 0; ks < KSPLIT; ++ks) {
        wgt[ks].x = exp2f(m4[ks].x - M.x); wgt[ks].y = exp2f(m4[ks].y - M.y);
        wgt[ks].z = exp2f(m4[ks].z - M.z); wgt[ks].w = exp2f(m4[ks].w - M.w);
        den.x += l4[ks].x * wgt[ks].x; den.y += l4[ks].y * wgt[ks].y;
        den.z += l4[ks].z * wgt[ks].z; den.w += l4[ks].w * wgt[ks].w;
    }
    float4 inv = {1.f/den.x, 1.f/den.y, 1.f/den.z, 1.f/den.w};
    #pragma unroll
    for (int cc = 0; cc < 4; ++cc) {
        int c = cq*4 + cc;
        float4 acc = {0.f, 0.f, 0.f, 0.f};
        #pragma unroll
        for (int ks = 0; ks < KSPLIT; ++ks) {
            const float* part = part_base_c(ws, b*KSPLIT + ks);
            float4 p4 = *(const float4*)&part[(size_t)c*TOK + t];
            acc.x += p4.x * wgt[ks].x; acc.y += p4.y * wgt[ks].y;
            acc.z += p4.z * wgt[ks].z; acc.w += p4.w * wgt[ks].w;
        }
        float4 o4 = {acc.x*inv.x, acc.y*inv.y, acc.z*inv.z, acc.w*inv.w};
        *(float4*)&out[(size_t)(b*64 + c)*TOK + t] = o4;
    }
}

extern "C" void kernel_launch(void* const* d_in, const int* in_sizes, int n_in,
                              void* d_out, int out_size, void* d_ws, size_t ws_size,
                              hipStream_t stream)
{
    const float* frames = (const float*)d_in[0];
    const float* w1 = (const float*)d_in[1];
    const float* b1 = (const float*)d_in[2];
    const float* w2 = (const float*)d_in[3];
    const float* b2 = (const float*)d_in[4];
    const float* qw = (const float*)d_in[5];
    const float* qb = (const float*)d_in[6];
    const float* kw = (const float*)d_in[7];
    const float* kb = (const float*)d_in[8];
    const float* vw = (const float*)d_in[9];
    const float* vb = (const float*)d_in[10];
    float* ws = (float*)d_ws;
    float* out = (float*)d_out;

    hipLaunchKernelGGL(conv1_kernel, dim3(288), dim3(256), 0, stream,
                       frames, w1, b1, w2, b2, qw, qb, kw, kb, vw, vb, ws);
    hipLaunchKernelGGL(conv2qkv_kernel, dim3(288), dim3(256), 0, stream, ws);
    hipLaunchKernelGGL(attn_kernel, dim3(2*72*KSPLIT), dim3(512), 0, stream, ws);
    hipLaunchKernelGGL(recombine_kernel, dim3(288), dim3(256), 0, stream, ws, out);
}